// Round 6
// baseline (119.164 us; speedup 1.0000x reference)
//
#include <hip/hip_runtime.h>

// FullRelPos: out[b,hw,g, kh*32+kw] = attn[...] + lh[kh] + lw[kw]
//   lh[k] = dot(q[row, 0:32],  rel_emb_h[k-h+31, :])
//   lw[k] = dot(q[row,32:64],  rel_emb_w[k-w+31, :])
//
// R5 fused hit 4.76 TB/s logical (76% of copy ceiling): coarse per-wave 32KB
// streams -> scattered DRAM access set. This round: split logits to d_ws
// (16 MB), then a fill-shaped stream kernel — dense marching window, one 4KB
// row per block-iteration, thread u <-> float4 u. Logit adds = cheap cached
// loads; no cross-lane ops anywhere in the stream.

#define QL 1024    // H*W

typedef float floatx4 __attribute__((ext_vector_type(4)));

// ---------- kernel 1: lg[row][0:32]=lh, [32:64]=lw ----------
__global__ __launch_bounds__(256) void logits_kernel(
    const float* __restrict__ q,
    const float* __restrict__ reh,
    const float* __restrict__ rew,
    float* __restrict__ lg,
    int ntasks)
{
    const int lane = threadIdx.x & 63;
    const int wid  = blockIdx.x * 4 + (threadIdx.x >> 6);
    const int nwaves = gridDim.x * 4;

    for (int t = wid; t < ntasks; t += nwaves) {
        const int hw = t & (QL - 1);         // task = (b, hw); 8 g-rows per task
        const int h  = hw >> 5;
        const int w  = hw & 31;
        const size_t r0 = (size_t)t << 3;

        const int k = lane & 31;             // lanes 0..31 -> lh[k], 32..63 -> lw[k]
        const float4* e4 = (lane < 32)
            ? (const float4*)(reh + (size_t)(k - h + 31) * 32)
            : (const float4*)(rew + (size_t)(k - w + 31) * 32);
        const float* qbase = q + r0 * 64 + (lane & 32);

        float acc[8];
        #pragma unroll
        for (int g = 0; g < 8; ++g) acc[g] = 0.f;
        #pragma unroll
        for (int c4 = 0; c4 < 8; ++c4) {
            const float4 ev = e4[c4];
            #pragma unroll
            for (int g = 0; g < 8; ++g) {
                const float4 qv = *(const float4*)(qbase + g * 64 + c4 * 4);
                acc[g] += qv.x * ev.x + qv.y * ev.y + qv.z * ev.z + qv.w * ev.w;
            }
        }
        #pragma unroll
        for (int g = 0; g < 8; ++g)
            lg[(r0 + g) * 64 + lane] = acc[g];   // 256B coalesced per store
    }
}

// ---------- kernel 2: fill-shaped stream add ----------
// Block-iteration handles 2 adjacent 4KB rows; all 2048 blocks together form
// a dense 16MB window marching through attn/out in lockstep (fill-like).
__global__ __launch_bounds__(256) void stream_kernel(
    const float* __restrict__ attn,
    const float* __restrict__ lg,
    float* __restrict__ out,
    int nrows)
{
    const int u   = threadIdx.x;        // float4 index within row, 0..255
    const int kh  = u >> 3;             // kh for this unit
    const int kw4 = (u & 7) * 4;        // kw base for this unit

    const int rstep = gridDim.x * 2;
    for (int rb = blockIdx.x * 2; rb < nrows; rb += rstep) {
        const float4* a0 = (const float4*)(attn + (size_t)rb * QL);
        const float4* a1 = (const float4*)(attn + (size_t)(rb + 1) * QL);
        const float*  l0 = lg + (size_t)rb * 64;
        const float*  l1 = lg + (size_t)(rb + 1) * 64;

        // issue all independent loads up front
        const float4 av0 = a0[u];
        const float4 av1 = a1[u];
        const float  lh0 = l0[kh];
        const float  lh1 = l1[kh];
        const float4 lw0 = *(const float4*)(l0 + 32 + kw4);
        const float4 lw1 = *(const float4*)(l1 + 32 + kw4);

        floatx4 o;
        o.x = av0.x + lh0 + lw0.x;
        o.y = av0.y + lh0 + lw0.y;
        o.z = av0.z + lh0 + lw0.z;
        o.w = av0.w + lh0 + lw0.w;
        __builtin_nontemporal_store(o, (floatx4*)(out + (size_t)rb * QL) + u);
        o.x = av1.x + lh1 + lw1.x;
        o.y = av1.y + lh1 + lw1.y;
        o.z = av1.z + lh1 + lw1.z;
        o.w = av1.w + lh1 + lw1.w;
        __builtin_nontemporal_store(o, (floatx4*)(out + (size_t)(rb + 1) * QL) + u);
    }
}

// ---------- fallback (R5 fused) if workspace too small ----------
__global__ __launch_bounds__(256) void relpos_fused2_kernel(
    const float* __restrict__ q,
    const float* __restrict__ attn,
    const float* __restrict__ reh,
    const float* __restrict__ rew,
    float* __restrict__ out,
    int ntasks)
{
    const int lane = threadIdx.x & 63;
    const int wid  = blockIdx.x * 4 + (threadIdx.x >> 6);
    const int nwaves = gridDim.x * 4;

    for (int t = wid; t < ntasks; t += nwaves) {
        const int hw = t & (QL - 1);
        const int h  = hw >> 5;
        const int w  = hw & 31;
        const size_t r0 = (size_t)t << 3;

        const int k = lane & 31;
        const float4* e4 = (lane < 32)
            ? (const float4*)(reh + (size_t)(k - h + 31) * 32)
            : (const float4*)(rew + (size_t)(k - w + 31) * 32);
        const float* qbase = q + r0 * 64 + (lane & 32);

        float acc[8];
        #pragma unroll
        for (int g = 0; g < 8; ++g) acc[g] = 0.f;
        #pragma unroll
        for (int c4 = 0; c4 < 8; ++c4) {
            const float4 ev = e4[c4];
            #pragma unroll
            for (int g = 0; g < 8; ++g) {
                const float4 qv = *(const float4*)(qbase + g * 64 + c4 * 4);
                acc[g] += qv.x * ev.x + qv.y * ev.y + qv.z * ev.z + qv.w * ev.w;
            }
        }
        const int kw0 = (lane << 2) & 31;
        const int kh0 = lane >> 3;
        float lh[8][4], lw[8][4];
        #pragma unroll
        for (int g = 0; g < 8; ++g) {
            const float a = acc[g];
            lh[g][0] = __shfl(a, kh0,      64);
            lh[g][1] = __shfl(a, kh0 + 8,  64);
            lh[g][2] = __shfl(a, kh0 + 16, 64);
            lh[g][3] = __shfl(a, kh0 + 24, 64);
            lw[g][0] = __shfl(a, 32 + kw0,     64);
            lw[g][1] = __shfl(a, 32 + kw0 + 1, 64);
            lw[g][2] = __shfl(a, 32 + kw0 + 2, 64);
            lw[g][3] = __shfl(a, 32 + kw0 + 3, 64);
        }
        const float4* abase = (const float4*)(attn + r0 * QL);
        floatx4*      obase = (floatx4*)(out  + r0 * QL);
        float4 buf[2][4];
        #pragma unroll
        for (int j = 0; j < 4; ++j)
            buf[0][j] = abase[lane + 64 * j];
        #pragma unroll
        for (int g = 0; g < 8; ++g) {
            if (g < 7) {
                const float4* anext = abase + (size_t)(g + 1) * 256;
                #pragma unroll
                for (int j = 0; j < 4; ++j)
                    buf[(g + 1) & 1][j] = anext[lane + 64 * j];
            }
            floatx4* orow = obase + (size_t)g * 256;
            #pragma unroll
            for (int j = 0; j < 4; ++j) {
                const float4 a = buf[g & 1][j];
                const float tl = lh[g][j];
                floatx4 o;
                o.x = a.x + tl + lw[g][0];
                o.y = a.y + tl + lw[g][1];
                o.z = a.z + tl + lw[g][2];
                o.w = a.w + tl + lw[g][3];
                __builtin_nontemporal_store(o, &orow[lane + 64 * j]);
            }
        }
    }
}

extern "C" void kernel_launch(void* const* d_in, const int* in_sizes, int n_in,
                              void* d_out, int out_size, void* d_ws, size_t ws_size,
                              hipStream_t stream) {
    const float* q    = (const float*)d_in[0];
    const float* attn = (const float*)d_in[1];
    const float* reh  = (const float*)d_in[2];
    const float* rew  = (const float*)d_in[3];
    float* out = (float*)d_out;

    const int nrows  = in_sizes[1] / QL;   // B * QL * G = 65536
    const int ntasks = nrows >> 3;         // 8192

    const size_t lg_bytes = (size_t)nrows * 64 * sizeof(float);  // 16 MB
    if (ws_size >= lg_bytes) {
        float* lg = (float*)d_ws;
        logits_kernel<<<2048, 256, 0, stream>>>(q, reh, rew, lg, ntasks);
        stream_kernel<<<2048, 256, 0, stream>>>(attn, lg, out, nrows);
    } else {
        relpos_fused2_kernel<<<2048, 256, 0, stream>>>(q, attn, reh, rew, out, ntasks);
    }
}